// Round 9
// baseline (621.969 us; speedup 1.0000x reference)
//
#include <hip/hip_runtime.h>
#include <cstdint>

#define B_ 32
#define N_ 64
#define H_ 128
#define S_ 100
#define C_ 16
#define SIGMA_ 0.5f

// output layout (floats): x_new | adj_new | assignments | x_emb | mask_new
#define OFF_XNEW 0
#define OFF_ADJN 262144
#define OFF_ASGN 393216
#define OFF_XEMB 598016
#define OFF_MSKN 860160

// ws layout (bytes)
#define WS_NCL_OFF   0            // 3200 int
#define WS_ABITS_OFF 16384        // 32*64 u64
#define WS_MBITS_OFF 32768        // 32 u64
#define WS_CONC_OFF  65536        // 3200*64 int = 819200
#define WS_CM_OFF    917504       // 3200*64 u64 = 1638400
#define WS_ADJB_OFF  2555904      // 3200*64 u64 = 1638400
#define WS_XE_OFF    4194304      // 32*64*128 f32 = 1048576
#define WS_PART_OFF  5242880      // 3200*8192 bf16 = 52428800
#define WS_NEED      57671680ull

__device__ __forceinline__ unsigned short f2bf(float f) {   // RNE, finite inputs
    unsigned int u = __float_as_uint(f);
    u += 0x7fffu + ((u >> 16) & 1u);
    return (unsigned short)(u >> 16);
}
__device__ __forceinline__ float bf2f(unsigned short h) {
    return __uint_as_float(((unsigned int)h) << 16);
}

// ---- mask dtype sniffing: mask[0,0] is guaranteed true (counts >= 32) ----
__device__ __forceinline__ int read_mask_elem(const void* mp, int idx) {
    const unsigned int* u = (const unsigned int*)mp;
    const unsigned int w0 = u[0], w1 = u[1];
    if (w0 == 1u) {
        if (w1 == 1u) return ((const int*)mp)[idx] != 0;
        return ((const int*)mp)[2 * idx] != 0;                 // int64
    }
    if (w0 == 0x3f800000u) return ((const float*)mp)[idx] != 0.0f;
    if (w0 == 0u) return ((const double*)mp)[idx] != 0.0;
    return ((const unsigned char*)mp)[idx] != 0;
}

// ============ Kernel A: one GCN layer, column-chunked (grid 32 x 8) ============
__global__ __launch_bounds__(256) void gcn_stage(
    const float* __restrict__ Xin, const float* __restrict__ adj,
    const void* __restrict__ maskp,
    const float* __restrict__ W, const float* __restrict__ bias,
    float* __restrict__ Xout,
    unsigned long long* __restrict__ abits_ws,
    unsigned long long* __restrict__ mbits_ws, int emit_bits)
{
    const int b = blockIdx.x, cc = blockIdx.y;
    const int t = threadIdx.x;
    const int tj = t & 63, tc = t >> 6;          // node tj, col-quad tc (4 cols)
    __shared__ float Xs[N_][129];
    __shared__ float An[N_][65];
    __shared__ float Hc[N_][20];
    __shared__ float dsh[N_];
    __shared__ unsigned long long mb_sh;

    if (t < 64) {
        const int mv = read_mask_elem(maskp, b * N_ + t);
        const unsigned long long bal = __ballot(mv != 0);
        if (t == 0) { mb_sh = bal; if (emit_bits && cc == 0) mbits_ws[b] = bal; }
    }
    for (int row = (t >> 6); row < N_; row += 4) {
        const int j = t & 63;
        const float v = adj[((size_t)b * N_ + row) * N_ + j];
        const unsigned long long bal = __ballot(v > 0.0f);
        if (emit_bits && cc == 0 && j == 0) abits_ws[b * N_ + row] = bal;
        An[row][j] = (row == j) ? 1.0f : v;
    }
    for (int e = t; e < N_ * H_; e += 256)
        Xs[e >> 7][e & 127] = Xin[(size_t)b * N_ * H_ + e];
    __syncthreads();
    if (t < 64) {
        float s = 0.0f;
        for (int j = 0; j < N_; ++j) s += An[t][j];
        if (s < 1.0f) s = 1.0f;
        dsh[t] = 1.0f / sqrtf(s);
    }
    __syncthreads();
    for (int e = t; e < N_ * N_; e += 256) {
        const int i = e >> 6, j = e & 63;
        An[i][j] *= dsh[i] * dsh[j];
    }
    // stage 1: Hc[tj][4tc..4tc+4) = Xs[tj] @ W[:, chunk cols]
    {
        float a0 = 0, a1 = 0, a2 = 0, a3 = 0;
        const float* wp = W + cc * 16 + tc * 4;
        for (int d = 0; d < H_; ++d) {
            const float xv = Xs[tj][d];
            const float4 w = *(const float4*)(wp + d * H_);
            a0 += xv * w.x; a1 += xv * w.y; a2 += xv * w.z; a3 += xv * w.w;
        }
        float4 o; o.x = a0; o.y = a1; o.z = a2; o.w = a3;
        *(float4*)&Hc[tj][tc * 4] = o;
    }
    __syncthreads();
    // stage 2: out = relu(An @ Hc + bias) * mask
    {
        float c0 = 0, c1 = 0, c2 = 0, c3 = 0;
        for (int j2 = 0; j2 < N_; ++j2) {
            const float av = An[tj][j2];
            const float4 h = *(const float4*)&Hc[j2][tc * 4];
            c0 += av * h.x; c1 += av * h.y; c2 += av * h.z; c3 += av * h.w;
        }
        const float4 bq = *(const float4*)(bias + cc * 16 + tc * 4);
        const float m = ((mb_sh >> tj) & 1ull) ? 1.0f : 0.0f;
        float4 o;
        o.x = fmaxf(c0 + bq.x, 0.0f) * m; o.y = fmaxf(c1 + bq.y, 0.0f) * m;
        o.z = fmaxf(c2 + bq.z, 0.0f) * m; o.w = fmaxf(c3 + bq.w, 0.0f) * m;
        *(float4*)&Xout[(size_t)b * N_ * H_ + tj * H_ + cc * 16 + tc * 4] = o;
    }
}

// ---- helpers: reduce-scatter 16 values over 16 contiguous lanes ----
__device__ __forceinline__ float rscat16(float* v, int kg) {
#pragma unroll
    for (int i = 0; i < 8; ++i) {
        const float send = (kg & 8) ? v[i] : v[i + 8];
        const float recv = __shfl_xor(send, 8);
        v[i] = ((kg & 8) ? v[i + 8] : v[i]) + recv;
    }
#pragma unroll
    for (int i = 0; i < 4; ++i) {
        const float send = (kg & 4) ? v[i] : v[i + 4];
        const float recv = __shfl_xor(send, 4);
        v[i] = ((kg & 4) ? v[i + 4] : v[i]) + recv;
    }
#pragma unroll
    for (int i = 0; i < 2; ++i) {
        const float send = (kg & 2) ? v[i] : v[i + 2];
        const float recv = __shfl_xor(send, 2);
        v[i] = ((kg & 2) ? v[i + 2] : v[i]) + recv;
    }
    {
        const float send = (kg & 1) ? v[0] : v[1];
        const float recv = __shfl_xor(send, 1);
        v[0] = ((kg & 1) ? v[1] : v[0]) + recv;
    }
    return v[0];
}

__device__ __forceinline__ void argmax16(float bv, int kg, int* dst) {
    int bi = kg;
#pragma unroll
    for (int m = 1; m <= 8; m <<= 1) {
        const float ov = __shfl_xor(bv, m);
        const int   oi = __shfl_xor(bi, m);
        if (ov > bv || (ov == bv && oi < bi)) { bv = ov; bi = oi; }
    }
    if (kg == 0) *dst = bi;
}

// ============ Kernel B1: MLP + argmax, 2 samples/block, 8n x 8k per thread ============
// threads 0-127: sample blockIdx*2, threads 128-255: sample blockIdx*2+1.
// Per-sample: kg = tid&15 (k cols 8kg..8kg+8), ng = tid>>4 (nodes 8ng..8ng+8).
// cW1 staged per 16-d tile into LDS with REGISTER PREFETCH (load next tile during
// compute of current -> global latency hidden under FMAs).
__global__ __launch_bounds__(256) void mlp_kernel(
    const float* __restrict__ xemb, const float* __restrict__ noise,
    const float* __restrict__ cW1, const float* __restrict__ cb1,
    const float* __restrict__ cW2, const float* __restrict__ cb2,
    int* __restrict__ conc)
{
    const int t = threadIdx.x;
    const int samp = t >> 7;
    const int tid  = t & 127;
    const int kg = tid & 15;
    const int ng = tid >> 4;
    const int sb = blockIdx.x * 2 + samp;

    __shared__ float xa[2 * N_ * H_];   // 64 KB, per-sample halves, chunk-swizzled
    __shared__ float wb[16 * H_];       // 8 KB current cW1 K-tile

    // ---- stage xa for both samples: xa = xemb[b] + 0.5*noise[sb] ----
    // swizzle: chunk cc of row i stored at column cc ^ ((i&7) ^ (i>>3))
    {
        float4* x4 = (float4*)xa;
        for (int idx = t; idx < 2 * N_ * 32; idx += 256) {
            const int s = idx >> 11, r2 = idx & 2047;
            const int i = r2 >> 5, cc = r2 & 31;
            const int sbl = blockIdx.x * 2 + s;
            const int bl  = sbl & (B_ - 1);
            const float4 ev = ((const float4*)(xemb + (size_t)bl * N_ * H_))[r2];
            const float4 nv = ((const float4*)(noise + (size_t)sbl * N_ * H_))[r2];
            float4 v;
            v.x = ev.x + SIGMA_ * nv.x;  v.y = ev.y + SIGMA_ * nv.y;
            v.z = ev.z + SIGMA_ * nv.z;  v.w = ev.w + SIGMA_ * nv.w;
            x4[s * 2048 + i * 32 + (cc ^ ((i & 7) ^ (i >> 3)))] = v;
        }
    }

    float acc[8][8] = {};
    {
        const float4* x4s = (const float4*)(xa + samp * N_ * H_);
        const float4* wsrc = (const float4*)cW1;
        // prologue: prefetch tile 0 into registers
        float4 p0 = wsrc[t], p1 = wsrc[t + 256];
        const int gg = ng;                       // r ^ ng computed as (r ^ gg) below
#pragma unroll 1
        for (int kt = 0; kt < 8; ++kt) {
            __syncthreads();                     // xa ready (kt=0) / wb readers done
            ((float4*)wb)[t] = p0;
            ((float4*)wb)[t + 256] = p1;
            __syncthreads();                     // wb tile ready
            if (kt < 7) {                        // prefetch next tile (hidden by FMAs)
                p0 = wsrc[(kt + 1) * 512 + t];
                p1 = wsrc[(kt + 1) * 512 + t + 256];
            }
#pragma unroll
            for (int cc4 = 0; cc4 < 4; ++cc4) {
                const int cc = kt * 4 + cc4;
                float xv[8][4];
#pragma unroll
                for (int r = 0; r < 8; ++r) {
                    const float4 tmp = x4s[(8 * ng + r) * 32 + (cc ^ (r ^ gg))];
                    xv[r][0] = tmp.x; xv[r][1] = tmp.y; xv[r][2] = tmp.z; xv[r][3] = tmp.w;
                }
#pragma unroll
                for (int dd = 0; dd < 4; ++dd) {
                    const int dl = cc4 * 4 + dd;
                    const float4 wa = *(const float4*)(wb + dl * H_ + 8 * kg);
                    const float4 wc = *(const float4*)(wb + dl * H_ + 8 * kg + 4);
                    const float wf[8] = {wa.x, wa.y, wa.z, wa.w, wc.x, wc.y, wc.z, wc.w};
#pragma unroll
                    for (int j = 0; j < 8; ++j)
#pragma unroll
                        for (int r = 0; r < 8; ++r) acc[r][j] += xv[r][dd] * wf[j];
                }
            }
        }
    }
    // ---- logits + argmax (per node r of this thread's 8 nodes) ----
    {
        const float4 ba = *(const float4*)(cb1 + 8 * kg);
        const float4 bb = *(const float4*)(cb1 + 8 * kg + 4);
        const float bf[8] = {ba.x, ba.y, ba.z, ba.w, bb.x, bb.y, bb.z, bb.w};
        const float cb2v = cb2[kg];
#pragma unroll
        for (int r = 0; r < 8; ++r) {
            float h[8];
#pragma unroll
            for (int j = 0; j < 8; ++j) h[j] = fmaxf(acc[r][j] + bf[j], 0.0f);
            float pl[16] = {};
#pragma unroll
            for (int j = 0; j < 8; ++j) {
                const float4* w2r = (const float4*)(cW2 + (8 * kg + j) * C_);
                const float4 w0 = w2r[0], w1 = w2r[1], w2v = w2r[2], w3 = w2r[3];
                const float wf2[16] = {w0.x, w0.y, w0.z, w0.w, w1.x, w1.y, w1.z, w1.w,
                                       w2v.x, w2v.y, w2v.z, w2v.w, w3.x, w3.y, w3.z, w3.w};
#pragma unroll
                for (int c = 0; c < C_; ++c) pl[c] += h[j] * wf2[c];
            }
            const float l = rscat16(pl, kg) + cb2v;
            argmax16(l, kg, conc + sb * N_ + 8 * ng + r);
        }
    }
}

// ====== Kernel B2: components + labeling, ONE WAVE PER (s,b) (grid 800x256) ======
__global__ __launch_bounds__(256) void cluster_kernel(
    const int* __restrict__ conc,
    const unsigned long long* __restrict__ abits_ws,
    const unsigned long long* __restrict__ mbits_ws,
    unsigned long long* __restrict__ cm_ws,
    unsigned long long* __restrict__ adjbits,
    int* __restrict__ nclArr, float* __restrict__ asgn_out)
{
    const int w = threadIdx.x >> 6, lane = threadIdx.x & 63;
    const int sb = blockIdx.x * 4 + w;
    const int b = sb & (B_ - 1);
    __shared__ int cl[4][N_];
    __shared__ unsigned long long reachL[4][N_];
    __shared__ unsigned long long cmL[4][N_];
    __shared__ unsigned long long roL[4][N_];
    __shared__ unsigned long long abL[4][N_];

    const unsigned long long mb = mbits_ws[b];
    const unsigned long long abv = abits_ws[b * N_ + lane];
    cl[w][lane] = conc[sb * N_ + lane];
    abL[w][lane] = abv;
    cmL[w][lane] = 0ull; roL[w][lane] = 0ull;
    __syncthreads();

    const int masked = (int)((mb >> lane) & 1ull);
    unsigned long long reach = 0ull;
    if (masked) {
        const int ci = cl[w][lane];
        unsigned long long mm = abv & mb, em = 0ull;
        while (mm) {
            const int j = __builtin_ctzll(mm);
            if (cl[w][j] == ci) em |= (1ull << j);
            mm &= mm - 1;
        }
        reach = em | (1ull << lane);
    }
    reachL[w][lane] = reach;
    __syncthreads();
    for (;;) {
        unsigned long long r = reach;
        if (masked) {
            unsigned long long mm = reach & ~(1ull << lane);
            while (mm) {
                const int j = __builtin_ctzll(mm);
                r |= reachL[w][j];
                mm &= mm - 1;
            }
        }
        const int changed = (r != reach);
        __syncthreads();
        reachL[w][lane] = r;
        reach = r;
        if (!__syncthreads_or(changed)) break;
    }
    const int root = masked ? __builtin_ctzll(reach) : 0;
    const unsigned long long present = __ballot(masked && (root == lane));
    const int ncl = __popcll(present);
    const int a_i = masked ? (__popcll(present & ((1ull << root) - 1ull)) + 1) : 0;
    if (masked && root == lane) {
        unsigned long long ro = 0ull, mm = reach;
        while (mm) { const int j = __builtin_ctzll(mm); ro |= abL[w][j]; mm &= mm - 1; }
        cmL[w][a_i - 1] = reach;
        roL[w][a_i - 1] = ro;
    }
    __syncthreads();
    asgn_out[(size_t)sb * N_ + lane] = (float)a_i;
    cm_ws[(size_t)sb * N_ + lane] = cmL[w][lane];
    unsigned long long row = 0ull;
    if (lane < ncl) {
        const unsigned long long ro = roL[w][lane];
        for (int c2 = 0; c2 < ncl; ++c2)
            if (ro & cmL[w][c2]) row |= (1ull << c2);
    }
    adjbits[(size_t)sb * N_ + lane] = row;
    if (lane == 0) nclArr[sb] = ncl;
}

// ====== Kernel B3: per-sample cluster sums (gathered from inputs) -> bf16 partial ======
__global__ __launch_bounds__(256) void pool_kernel(
    const float* __restrict__ xemb, const float* __restrict__ noise,
    const unsigned long long* __restrict__ cm_ws,
    unsigned short* __restrict__ part)
{
    const int sb = blockIdx.x;
    const int b  = sb & (B_ - 1);
    const int t  = threadIdx.x;
    const float4* e4 = (const float4*)(xemb + (size_t)b * N_ * H_);
    const float4* n4 = (const float4*)(noise + (size_t)sb * N_ * H_);
    for (int e = t; e < N_ * 32; e += 256) {          // e = c*32 + d4
        const int c = e >> 5, d4 = e & 31;
        unsigned long long mm = cm_ws[(size_t)sb * N_ + c];
        float4 s = {0.f, 0.f, 0.f, 0.f};
        while (mm) {
            const int j = __builtin_ctzll(mm);
            const float4 ev = e4[j * 32 + d4];
            const float4 nv = n4[j * 32 + d4];
            s.x += ev.x + SIGMA_ * nv.x; s.y += ev.y + SIGMA_ * nv.y;
            s.z += ev.z + SIGMA_ * nv.z; s.w += ev.w + SIGMA_ * nv.w;
            mm &= mm - 1;
        }
        ushort4 o;
        o.x = f2bf(s.x); o.y = f2bf(s.y); o.z = f2bf(s.z); o.w = f2bf(s.w);
        *(ushort4*)&part[(size_t)sb * (N_ * H_) + e * 4] = o;
    }
}

// ============ Kernel C: reduce partials over samples -> means, mask_new ============
__global__ __launch_bounds__(256) void reduce_kernel(
    const unsigned short* __restrict__ part,
    const unsigned long long* __restrict__ adjbits,
    const int* __restrict__ nclArr, float* __restrict__ out)
{
    const int idx = blockIdx.x * 256 + threadIdx.x;
    if (idx < 65536) {                       // x_new: float4 of output per thread
        const int b = idx >> 11, rem = idx & 2047;
        float4 s = {0.f, 0.f, 0.f, 0.f};
        const unsigned short* p = part + (size_t)b * (N_ * H_) + rem * 4;
#pragma unroll 4
        for (int s_ = 0; s_ < S_; ++s_) {
            const ushort4 v = *(const ushort4*)(p + (size_t)s_ * (B_ * N_ * H_));
            s.x += bf2f(v.x); s.y += bf2f(v.y); s.z += bf2f(v.z); s.w += bf2f(v.w);
        }
        s.x *= 0.01f; s.y *= 0.01f; s.z *= 0.01f; s.w *= 0.01f;
        *(float4*)&out[OFF_XNEW + (size_t)b * (N_ * H_) + rem * 4] = s;
    } else if (idx < 65536 + 131072) {       // adj_new
        const int j = idx - 65536;
        const int b = j >> 12, c1 = (j >> 6) & 63, c2 = j & 63;
        int cnt = 0;
#pragma unroll 4
        for (int s_ = 0; s_ < S_; ++s_)
            cnt += (int)((adjbits[((size_t)s_ * B_ + b) * N_ + c1] >> c2) & 1ull);
        out[OFF_ADJN + j] = (float)cnt * 0.01f;
    } else if (idx < 65536 + 131072 + 2048) { // mask_new
        const int m = idx - 196608;
        const int b = m >> 6, k = m & 63;
        int mx = 0;
        for (int s_ = 0; s_ < S_; ++s_) {
            const int v = nclArr[s_ * B_ + b];
            mx = v > mx ? v : mx;
        }
        out[OFF_MSKN + m] = (k < mx) ? 1.0f : 0.0f;
    }
}

extern "C" void kernel_launch(void* const* d_in, const int* in_sizes, int n_in,
                              void* d_out, int out_size, void* d_ws, size_t ws_size,
                              hipStream_t stream) {
    (void)in_sizes; (void)n_in; (void)out_size; (void)ws_size;
    const float* x    = (const float*)d_in[0];
    const float* adj  = (const float*)d_in[1];
    const void*  mskp = d_in[2];
    const float* W1   = (const float*)d_in[3];
    const float* b1   = (const float*)d_in[4];
    const float* W2   = (const float*)d_in[5];
    const float* b2   = (const float*)d_in[6];
    const float* cW1  = (const float*)d_in[7];
    const float* cb1  = (const float*)d_in[8];
    const float* cW2  = (const float*)d_in[9];
    const float* cb2  = (const float*)d_in[10];
    const float* noise = (const float*)d_in[11];
    float* out = (float*)d_out;

    int* nclArr = (int*)d_ws;
    unsigned long long* abits_ws = (unsigned long long*)((char*)d_ws + WS_ABITS_OFF);
    unsigned long long* mbits_ws = (unsigned long long*)((char*)d_ws + WS_MBITS_OFF);
    int* conc = (int*)((char*)d_ws + WS_CONC_OFF);
    unsigned long long* cm_ws = (unsigned long long*)((char*)d_ws + WS_CM_OFF);
    unsigned long long* adjbits = (unsigned long long*)((char*)d_ws + WS_ADJB_OFF);
    float* xe_ws = (float*)((char*)d_ws + WS_XE_OFF);
    unsigned short* part = (unsigned short*)((char*)d_ws + WS_PART_OFF);

    float* xemb = out + OFF_XEMB;

    gcn_stage<<<dim3(B_, 8), 256, 0, stream>>>(x, adj, mskp, W1, b1, xe_ws,
                                               abits_ws, mbits_ws, 1);
    gcn_stage<<<dim3(B_, 8), 256, 0, stream>>>(xe_ws, adj, mskp, W2, b2, xemb,
                                               abits_ws, mbits_ws, 0);
    mlp_kernel<<<S_ * B_ / 2, 256, 0, stream>>>(xemb, noise, cW1, cb1, cW2, cb2, conc);
    cluster_kernel<<<S_ * B_ / 4, 256, 0, stream>>>(conc, abits_ws, mbits_ws,
                                                    cm_ws, adjbits, nclArr,
                                                    out + OFF_ASGN);
    pool_kernel<<<S_ * B_, 256, 0, stream>>>(xemb, noise, cm_ws, part);
    reduce_kernel<<<(65536 + 131072 + 2048) / 256, 256, 0, stream>>>(
        part, adjbits, nclArr, out);
}

// Round 10
// 464.697 us; speedup vs baseline: 1.3384x; 1.3384x over previous
//
#include <hip/hip_runtime.h>
#include <cstdint>

#define B_ 32
#define N_ 64
#define H_ 128
#define S_ 100
#define C_ 16
#define SIGMA_ 0.5f

// output layout (floats): x_new | adj_new | assignments | x_emb | mask_new
#define OFF_XNEW 0
#define OFF_ADJN 262144
#define OFF_ASGN 393216
#define OFF_XEMB 598016
#define OFF_MSKN 860160

// ws layout (bytes)
#define WS_NCL_OFF   0            // 3200 int
#define WS_ABITS_OFF 16384        // 32*64 u64
#define WS_MBITS_OFF 32768        // 32 u64
#define WS_CONC_OFF  65536        // 3200*64 int = 819200
#define WS_CM_OFF    917504       // 3200*64 u64 = 1638400
#define WS_ADJB_OFF  2555904      // 3200*64 u64 = 1638400
#define WS_XE_OFF    4194304      // 32*64*128 f32 = 1048576
#define WS_PART_OFF  5242880      // 3200*8192 bf16 = 52428800
#define WS_NEED      57671680ull

// xa row swizzle: chunk cc of row i stored at column cc ^ SWZ(i)
#define SWZ(i) (((i) & 7) ^ ((((i) >> 3) & 1) << 1))

__device__ __forceinline__ unsigned short f2bf(float f) {   // RNE, finite inputs
    unsigned int u = __float_as_uint(f);
    u += 0x7fffu + ((u >> 16) & 1u);
    return (unsigned short)(u >> 16);
}
__device__ __forceinline__ float bf2f(unsigned short h) {
    return __uint_as_float(((unsigned int)h) << 16);
}

// ---- mask dtype sniffing: mask[0,0] is guaranteed true (counts >= 32) ----
__device__ __forceinline__ int read_mask_elem(const void* mp, int idx) {
    const unsigned int* u = (const unsigned int*)mp;
    const unsigned int w0 = u[0], w1 = u[1];
    if (w0 == 1u) {
        if (w1 == 1u) return ((const int*)mp)[idx] != 0;
        return ((const int*)mp)[2 * idx] != 0;                 // int64
    }
    if (w0 == 0x3f800000u) return ((const float*)mp)[idx] != 0.0f;
    if (w0 == 0u) return ((const double*)mp)[idx] != 0.0;
    return ((const unsigned char*)mp)[idx] != 0;
}

// ============ Kernel A: one GCN layer, column-chunked (grid 32 x 8) ============
__global__ __launch_bounds__(256) void gcn_stage(
    const float* __restrict__ Xin, const float* __restrict__ adj,
    const void* __restrict__ maskp,
    const float* __restrict__ W, const float* __restrict__ bias,
    float* __restrict__ Xout,
    unsigned long long* __restrict__ abits_ws,
    unsigned long long* __restrict__ mbits_ws, int emit_bits)
{
    const int b = blockIdx.x, cc = blockIdx.y;
    const int t = threadIdx.x;
    const int tj = t & 63, tc = t >> 6;          // node tj, col-quad tc (4 cols)
    __shared__ float Xs[N_][129];
    __shared__ float An[N_][65];
    __shared__ float Hc[N_][20];
    __shared__ float dsh[N_];
    __shared__ unsigned long long mb_sh;

    if (t < 64) {
        const int mv = read_mask_elem(maskp, b * N_ + t);
        const unsigned long long bal = __ballot(mv != 0);
        if (t == 0) { mb_sh = bal; if (emit_bits && cc == 0) mbits_ws[b] = bal; }
    }
    for (int row = (t >> 6); row < N_; row += 4) {
        const int j = t & 63;
        const float v = adj[((size_t)b * N_ + row) * N_ + j];
        const unsigned long long bal = __ballot(v > 0.0f);
        if (emit_bits && cc == 0 && j == 0) abits_ws[b * N_ + row] = bal;
        An[row][j] = (row == j) ? 1.0f : v;
    }
    for (int e = t; e < N_ * H_; e += 256)
        Xs[e >> 7][e & 127] = Xin[(size_t)b * N_ * H_ + e];
    __syncthreads();
    if (t < 64) {
        float s = 0.0f;
        for (int j = 0; j < N_; ++j) s += An[t][j];
        if (s < 1.0f) s = 1.0f;
        dsh[t] = 1.0f / sqrtf(s);
    }
    __syncthreads();
    for (int e = t; e < N_ * N_; e += 256) {
        const int i = e >> 6, j = e & 63;
        An[i][j] *= dsh[i] * dsh[j];
    }
    // stage 1: Hc[tj][4tc..4tc+4) = Xs[tj] @ W[:, chunk cols]
    {
        float a0 = 0, a1 = 0, a2 = 0, a3 = 0;
        const float* wp = W + cc * 16 + tc * 4;
        for (int d = 0; d < H_; ++d) {
            const float xv = Xs[tj][d];
            const float4 w = *(const float4*)(wp + d * H_);
            a0 += xv * w.x; a1 += xv * w.y; a2 += xv * w.z; a3 += xv * w.w;
        }
        float4 o; o.x = a0; o.y = a1; o.z = a2; o.w = a3;
        *(float4*)&Hc[tj][tc * 4] = o;
    }
    __syncthreads();
    // stage 2: out = relu(An @ Hc + bias) * mask
    {
        float c0 = 0, c1 = 0, c2 = 0, c3 = 0;
        for (int j2 = 0; j2 < N_; ++j2) {
            const float av = An[tj][j2];
            const float4 h = *(const float4*)&Hc[j2][tc * 4];
            c0 += av * h.x; c1 += av * h.y; c2 += av * h.z; c3 += av * h.w;
        }
        const float4 bq = *(const float4*)(bias + cc * 16 + tc * 4);
        const float m = ((mb_sh >> tj) & 1ull) ? 1.0f : 0.0f;
        float4 o;
        o.x = fmaxf(c0 + bq.x, 0.0f) * m; o.y = fmaxf(c1 + bq.y, 0.0f) * m;
        o.z = fmaxf(c2 + bq.z, 0.0f) * m; o.w = fmaxf(c3 + bq.w, 0.0f) * m;
        *(float4*)&Xout[(size_t)b * N_ * H_ + tj * H_ + cc * 16 + tc * 4] = o;
    }
}

// ---- helpers: reduce-scatter 16 values over 16 contiguous lanes ----
__device__ __forceinline__ float rscat16(float* v, int kg) {
#pragma unroll
    for (int i = 0; i < 8; ++i) {
        const float send = (kg & 8) ? v[i] : v[i + 8];
        const float recv = __shfl_xor(send, 8);
        v[i] = ((kg & 8) ? v[i + 8] : v[i]) + recv;
    }
#pragma unroll
    for (int i = 0; i < 4; ++i) {
        const float send = (kg & 4) ? v[i] : v[i + 4];
        const float recv = __shfl_xor(send, 4);
        v[i] = ((kg & 4) ? v[i + 4] : v[i]) + recv;
    }
#pragma unroll
    for (int i = 0; i < 2; ++i) {
        const float send = (kg & 2) ? v[i] : v[i + 2];
        const float recv = __shfl_xor(send, 2);
        v[i] = ((kg & 2) ? v[i + 2] : v[i]) + recv;
    }
    {
        const float send = (kg & 1) ? v[0] : v[1];
        const float recv = __shfl_xor(send, 1);
        v[0] = ((kg & 1) ? v[1] : v[0]) + recv;
    }
    return v[0];
}

__device__ __forceinline__ void argmax16(float bv, int kg, int* dst) {
    int bi = kg;
#pragma unroll
    for (int m = 1; m <= 8; m <<= 1) {
        const float ov = __shfl_xor(bv, m);
        const int   oi = __shfl_xor(bi, m);
        if (ov > bv || (ov == bv && oi < bi)) { bv = ov; bi = oi; }
    }
    if (kg == 0) *dst = bi;
}

// ============ Kernel B1: MLP + argmax, 1 sample/block, conflict-free LDS ============
// kg = t&15 (k cols 8kg..8kg+8), ng = t>>4 (nodes 4ng..4ng+4).
// xa: row-swizzled (SWZ) -> xv reads 1-pass; wb: skewed layout -> 2-way max.
// cW1 16-d tiles register-prefetched (global latency hidden under FMAs).
__global__ __launch_bounds__(256) void mlp_kernel(
    const float* __restrict__ xemb, const float* __restrict__ noise,
    const float* __restrict__ cW1, const float* __restrict__ cb1,
    const float* __restrict__ cW2, const float* __restrict__ cb2,
    int* __restrict__ conc)
{
    const int t = threadIdx.x;
    const int sb = blockIdx.x;
    const int b  = sb & (B_ - 1);
    const int kg = t & 15;
    const int ng = t >> 4;

    __shared__ float xa[N_ * H_];     // 32 KB, row-swizzled
    __shared__ float wb[16 * 144];    // 9 KB, skewed: row dl stride 144 floats

    // ---- stage xa = xemb[b] + 0.5*noise[sb] ----
    {
        const float4* e4 = (const float4*)(xemb + (size_t)b * N_ * H_);
        const float4* n4 = (const float4*)(noise + (size_t)sb * N_ * H_);
        float4* x4 = (float4*)xa;
        for (int idx = t; idx < N_ * 32; idx += 256) {
            const int i = idx >> 5, cc = idx & 31;
            const float4 ev = e4[idx], nv = n4[idx];
            float4 v;
            v.x = ev.x + SIGMA_ * nv.x;  v.y = ev.y + SIGMA_ * nv.y;
            v.z = ev.z + SIGMA_ * nv.z;  v.w = ev.w + SIGMA_ * nv.w;
            x4[i * 32 + (cc ^ SWZ(i))] = v;
        }
    }

    // wb staging dest (float4 units) for source float4 f: row dl=f>>5, q=f&31,
    // chunk c=q>>1, half h=q&1 -> dl*36 + c*2 + (c>>2) + h
    const int f0 = t, f1 = t + 256;
    const int d0 = (f0 >> 5) * 36 + ((f0 & 31) >> 1) * 2 + (((f0 & 31) >> 1) >> 2) + (f0 & 1);
    const int d1 = (f1 >> 5) * 36 + ((f1 & 31) >> 1) * 2 + (((f1 & 31) >> 1) >> 2) + (f1 & 1);
    const int kgoff = kg * 2 + (kg >> 2);        // float4 index of this thread's w-chunk

    float acc[4][8] = {};
    {
        const float4* x4 = (const float4*)xa;
        const float4* wsrc = (const float4*)cW1;
        float4* wb4 = (float4*)wb;
        // per-thread row constants (4 rows: 4ng..4ng+3)
        int rowb[4], rsw[4];
#pragma unroll
        for (int r = 0; r < 4; ++r) {
            const int i = 4 * ng + r;
            rowb[r] = i * 32;
            rsw[r]  = SWZ(i);
        }
        float4 p0 = wsrc[t], p1 = wsrc[t + 256];     // prefetch tile 0
#pragma unroll 1
        for (int kt = 0; kt < 8; ++kt) {
            __syncthreads();                          // xa ready / wb readers done
            wb4[d0] = p0;
            wb4[d1] = p1;
            __syncthreads();                          // wb tile ready
            if (kt < 7) {                             // prefetch next (hidden by FMAs)
                p0 = wsrc[(kt + 1) * 512 + t];
                p1 = wsrc[(kt + 1) * 512 + t + 256];
            }
#pragma unroll
            for (int cc4 = 0; cc4 < 4; ++cc4) {
                const int cc = kt * 4 + cc4;
                float xv[4][4];
#pragma unroll
                for (int r = 0; r < 4; ++r) {
                    const float4 tmp = x4[rowb[r] + (cc ^ rsw[r])];
                    xv[r][0] = tmp.x; xv[r][1] = tmp.y; xv[r][2] = tmp.z; xv[r][3] = tmp.w;
                }
#pragma unroll
                for (int dd = 0; dd < 4; ++dd) {
                    const int dl = cc4 * 4 + dd;
                    const float4 wa = wb4[dl * 36 + kgoff];
                    const float4 wc = wb4[dl * 36 + kgoff + 1];
                    const float wf[8] = {wa.x, wa.y, wa.z, wa.w, wc.x, wc.y, wc.z, wc.w};
#pragma unroll
                    for (int j = 0; j < 8; ++j)
#pragma unroll
                        for (int r = 0; r < 4; ++r) acc[r][j] += xv[r][dd] * wf[j];
                }
            }
        }
    }
    // ---- logits + argmax ----
    {
        const float4 ba = *(const float4*)(cb1 + 8 * kg);
        const float4 bb = *(const float4*)(cb1 + 8 * kg + 4);
        const float bf[8] = {ba.x, ba.y, ba.z, ba.w, bb.x, bb.y, bb.z, bb.w};
        const float cb2v = cb2[kg];
#pragma unroll
        for (int r = 0; r < 4; ++r) {
            float h[8];
#pragma unroll
            for (int j = 0; j < 8; ++j) h[j] = fmaxf(acc[r][j] + bf[j], 0.0f);
            float pl[16] = {};
#pragma unroll
            for (int j = 0; j < 8; ++j) {
                const float4* w2r = (const float4*)(cW2 + (8 * kg + j) * C_);
                const float4 w0 = w2r[0], w1 = w2r[1], w2v = w2r[2], w3 = w2r[3];
                const float wf2[16] = {w0.x, w0.y, w0.z, w0.w, w1.x, w1.y, w1.z, w1.w,
                                       w2v.x, w2v.y, w2v.z, w2v.w, w3.x, w3.y, w3.z, w3.w};
#pragma unroll
                for (int c = 0; c < C_; ++c) pl[c] += h[j] * wf2[c];
            }
            const float l = rscat16(pl, kg) + cb2v;
            argmax16(l, kg, conc + sb * N_ + 4 * ng + r);
        }
    }
}

// ====== Kernel B2: components + labeling, ONE WAVE PER (s,b) (grid 800x256) ======
__global__ __launch_bounds__(256) void cluster_kernel(
    const int* __restrict__ conc,
    const unsigned long long* __restrict__ abits_ws,
    const unsigned long long* __restrict__ mbits_ws,
    unsigned long long* __restrict__ cm_ws,
    unsigned long long* __restrict__ adjbits,
    int* __restrict__ nclArr, float* __restrict__ asgn_out)
{
    const int w = threadIdx.x >> 6, lane = threadIdx.x & 63;
    const int sb = blockIdx.x * 4 + w;
    const int b = sb & (B_ - 1);
    __shared__ int cl[4][N_];
    __shared__ unsigned long long reachL[4][N_];
    __shared__ unsigned long long cmL[4][N_];
    __shared__ unsigned long long roL[4][N_];
    __shared__ unsigned long long abL[4][N_];

    const unsigned long long mb = mbits_ws[b];
    const unsigned long long abv = abits_ws[b * N_ + lane];
    cl[w][lane] = conc[sb * N_ + lane];
    abL[w][lane] = abv;
    cmL[w][lane] = 0ull; roL[w][lane] = 0ull;
    __syncthreads();

    const int masked = (int)((mb >> lane) & 1ull);
    unsigned long long reach = 0ull;
    if (masked) {
        const int ci = cl[w][lane];
        unsigned long long mm = abv & mb, em = 0ull;
        while (mm) {
            const int j = __builtin_ctzll(mm);
            if (cl[w][j] == ci) em |= (1ull << j);
            mm &= mm - 1;
        }
        reach = em | (1ull << lane);
    }
    reachL[w][lane] = reach;
    __syncthreads();
    for (;;) {
        unsigned long long r = reach;
        if (masked) {
            unsigned long long mm = reach & ~(1ull << lane);
            while (mm) {
                const int j = __builtin_ctzll(mm);
                r |= reachL[w][j];
                mm &= mm - 1;
            }
        }
        const int changed = (r != reach);
        __syncthreads();
        reachL[w][lane] = r;
        reach = r;
        if (!__syncthreads_or(changed)) break;
    }
    const int root = masked ? __builtin_ctzll(reach) : 0;
    const unsigned long long present = __ballot(masked && (root == lane));
    const int ncl = __popcll(present);
    const int a_i = masked ? (__popcll(present & ((1ull << root) - 1ull)) + 1) : 0;
    if (masked && root == lane) {
        unsigned long long ro = 0ull, mm = reach;
        while (mm) { const int j = __builtin_ctzll(mm); ro |= abL[w][j]; mm &= mm - 1; }
        cmL[w][a_i - 1] = reach;
        roL[w][a_i - 1] = ro;
    }
    __syncthreads();
    asgn_out[(size_t)sb * N_ + lane] = (float)a_i;
    cm_ws[(size_t)sb * N_ + lane] = cmL[w][lane];
    unsigned long long row = 0ull;
    if (lane < ncl) {
        const unsigned long long ro = roL[w][lane];
        for (int c2 = 0; c2 < ncl; ++c2)
            if (ro & cmL[w][c2]) row |= (1ull << c2);
    }
    adjbits[(size_t)sb * N_ + lane] = row;
    if (lane == 0) nclArr[sb] = ncl;
}

// ====== Kernel B3: per-sample cluster sums (gathered from inputs) -> bf16 partial ======
__global__ __launch_bounds__(256) void pool_kernel(
    const float* __restrict__ xemb, const float* __restrict__ noise,
    const unsigned long long* __restrict__ cm_ws,
    unsigned short* __restrict__ part)
{
    const int sb = blockIdx.x;
    const int b  = sb & (B_ - 1);
    const int t  = threadIdx.x;
    const float4* e4 = (const float4*)(xemb + (size_t)b * N_ * H_);
    const float4* n4 = (const float4*)(noise + (size_t)sb * N_ * H_);
    for (int e = t; e < N_ * 32; e += 256) {          // e = c*32 + d4
        const int c = e >> 5, d4 = e & 31;
        unsigned long long mm = cm_ws[(size_t)sb * N_ + c];
        float4 s = {0.f, 0.f, 0.f, 0.f};
        while (mm) {
            const int j = __builtin_ctzll(mm);
            const float4 ev = e4[j * 32 + d4];
            const float4 nv = n4[j * 32 + d4];
            s.x += ev.x + SIGMA_ * nv.x; s.y += ev.y + SIGMA_ * nv.y;
            s.z += ev.z + SIGMA_ * nv.z; s.w += ev.w + SIGMA_ * nv.w;
            mm &= mm - 1;
        }
        ushort4 o;
        o.x = f2bf(s.x); o.y = f2bf(s.y); o.z = f2bf(s.z); o.w = f2bf(s.w);
        *(ushort4*)&part[(size_t)sb * (N_ * H_) + e * 4] = o;
    }
}

// ============ Kernel C: reduce partials over samples -> means, mask_new ============
__global__ __launch_bounds__(256) void reduce_kernel(
    const unsigned short* __restrict__ part,
    const unsigned long long* __restrict__ adjbits,
    const int* __restrict__ nclArr, float* __restrict__ out)
{
    const int idx = blockIdx.x * 256 + threadIdx.x;
    if (idx < 65536) {                       // x_new: float4 of output per thread
        const int b = idx >> 11, rem = idx & 2047;
        float4 s = {0.f, 0.f, 0.f, 0.f};
        const unsigned short* p = part + (size_t)b * (N_ * H_) + rem * 4;
#pragma unroll 4
        for (int s_ = 0; s_ < S_; ++s_) {
            const ushort4 v = *(const ushort4*)(p + (size_t)s_ * (B_ * N_ * H_));
            s.x += bf2f(v.x); s.y += bf2f(v.y); s.z += bf2f(v.z); s.w += bf2f(v.w);
        }
        s.x *= 0.01f; s.y *= 0.01f; s.z *= 0.01f; s.w *= 0.01f;
        *(float4*)&out[OFF_XNEW + (size_t)b * (N_ * H_) + rem * 4] = s;
    } else if (idx < 65536 + 131072) {       // adj_new
        const int j = idx - 65536;
        const int b = j >> 12, c1 = (j >> 6) & 63, c2 = j & 63;
        int cnt = 0;
#pragma unroll 4
        for (int s_ = 0; s_ < S_; ++s_)
            cnt += (int)((adjbits[((size_t)s_ * B_ + b) * N_ + c1] >> c2) & 1ull);
        out[OFF_ADJN + j] = (float)cnt * 0.01f;
    } else if (idx < 65536 + 131072 + 2048) { // mask_new
        const int m = idx - 196608;
        const int b = m >> 6, k = m & 63;
        int mx = 0;
        for (int s_ = 0; s_ < S_; ++s_) {
            const int v = nclArr[s_ * B_ + b];
            mx = v > mx ? v : mx;
        }
        out[OFF_MSKN + m] = (k < mx) ? 1.0f : 0.0f;
    }
}

extern "C" void kernel_launch(void* const* d_in, const int* in_sizes, int n_in,
                              void* d_out, int out_size, void* d_ws, size_t ws_size,
                              hipStream_t stream) {
    (void)in_sizes; (void)n_in; (void)out_size; (void)ws_size;
    const float* x    = (const float*)d_in[0];
    const float* adj  = (const float*)d_in[1];
    const void*  mskp = d_in[2];
    const float* W1   = (const float*)d_in[3];
    const float* b1   = (const float*)d_in[4];
    const float* W2   = (const float*)d_in[5];
    const float* b2   = (const float*)d_in[6];
    const float* cW1  = (const float*)d_in[7];
    const float* cb1  = (const float*)d_in[8];
    const float* cW2  = (const float*)d_in[9];
    const float* cb2  = (const float*)d_in[10];
    const float* noise = (const float*)d_in[11];
    float* out = (float*)d_out;

    int* nclArr = (int*)d_ws;
    unsigned long long* abits_ws = (unsigned long long*)((char*)d_ws + WS_ABITS_OFF);
    unsigned long long* mbits_ws = (unsigned long long*)((char*)d_ws + WS_MBITS_OFF);
    int* conc = (int*)((char*)d_ws + WS_CONC_OFF);
    unsigned long long* cm_ws = (unsigned long long*)((char*)d_ws + WS_CM_OFF);
    unsigned long long* adjbits = (unsigned long long*)((char*)d_ws + WS_ADJB_OFF);
    float* xe_ws = (float*)((char*)d_ws + WS_XE_OFF);
    unsigned short* part = (unsigned short*)((char*)d_ws + WS_PART_OFF);

    float* xemb = out + OFF_XEMB;

    gcn_stage<<<dim3(B_, 8), 256, 0, stream>>>(x, adj, mskp, W1, b1, xe_ws,
                                               abits_ws, mbits_ws, 1);
    gcn_stage<<<dim3(B_, 8), 256, 0, stream>>>(xe_ws, adj, mskp, W2, b2, xemb,
                                               abits_ws, mbits_ws, 0);
    mlp_kernel<<<S_ * B_, 256, 0, stream>>>(xemb, noise, cW1, cb1, cW2, cb2, conc);
    cluster_kernel<<<S_ * B_ / 4, 256, 0, stream>>>(conc, abits_ws, mbits_ws,
                                                    cm_ws, adjbits, nclArr,
                                                    out + OFF_ASGN);
    pool_kernel<<<S_ * B_, 256, 0, stream>>>(xemb, noise, cm_ws, part);
    reduce_kernel<<<(65536 + 131072 + 2048) / 256, 256, 0, stream>>>(
        part, adjbits, nclArr, out);
}